// Round 15
// baseline (1352.372 us; speedup 1.0000x reference)
//
#include <hip/hip_runtime.h>
#include <hip/hip_bf16.h>
#include <cstdint>
#include <cmath>
#include <vector>
#include <algorithm>
#include <numeric>

// ---------------------------------------------------------------------------
// LapSWD loss. RNG = exact JAX partitionable threefry.
// R20: sortdiff __launch_bounds__ (512,4) -> (512,2). Spill diagnosis:
// VGPR_Count=64 == exactly va[32]+vb[32] live data -> allocator had ZERO
// temps, guaranteed scratch thrash; static count ~11k VALU/thread vs
// counters implying ~58k issue slots (6x anomaly). Cap 256 lets the
// compiler hold data + temps (~130-160 VGPR) spill-free; trade:
// 2 blocks/CU -> 1 block/CU (grid 512 = two clean rounds of 256).
// R19: row-granular extract (25 loads/7 outputs). R18: MFMA bf16-split gemm.
// R17: bias fold + parallel prep. R16: 32/thr merge-path. R13: separable down.
// ---------------------------------------------------------------------------

#define SIDX(i) ((i) ^ ((((i) >> 5) ^ ((i) >> 10)) & 31))
#define EXB 1024  // extract grid per half: 1024 blocks x 256 thr, grid-stride

typedef __attribute__((ext_vector_type(8))) short bf16x8;
typedef __attribute__((ext_vector_type(4))) float f32x4;
typedef __attribute__((ext_vector_type(4))) unsigned short us4;

struct RC { unsigned int rc[128]; };
struct Keys { uint32_t a[5]; uint32_t b[5]; };

// ---- threefry2x32 block cipher, exact JAX/XLA schedule ----
__host__ __device__ inline void tf2x32(uint32_t k0, uint32_t k1,
                                       uint32_t x0, uint32_t x1,
                                       uint32_t& o0, uint32_t& o1) {
  uint32_t k2 = k0 ^ k1 ^ 0x1BD11BDAu;
  x0 += k0; x1 += k1;
#define TFR(r) { x0 += x1; x1 = (x1 << r) | (x1 >> (32 - r)); x1 ^= x0; }
  TFR(13) TFR(15) TFR(26) TFR(6)   x0 += k1; x1 += k2 + 1u;
  TFR(17) TFR(29) TFR(16) TFR(24)  x0 += k2; x1 += k0 + 2u;
  TFR(13) TFR(15) TFR(26) TFR(6)   x0 += k0; x1 += k1 + 3u;
  TFR(17) TFR(29) TFR(16) TFR(24)  x0 += k1; x1 += k2 + 4u;
  TFR(13) TFR(15) TFR(26) TFR(6)   x0 += k2; x1 += k0 + 5u;
#undef TFR
  o0 = x0; o1 = x1;
}

// ---- host tables (pure constants; computed once at library load) ----
struct HostTables {
  RC rcs[5];
  uint32_t kp0[5], kp1[5];
  HostTables() {
    static const int Hs[5] = {256, 128, 64, 32, 16};
    for (int l = 0; l < 5; ++l) {
      uint32_t f0, f1;
      tf2x32(0u, 42u, 0u, (uint32_t)l, f0, f1);  // fold_in(key(42), l)
      uint32_t ik0, ik1;
      tf2x32(f0, f1, 0u, 0u, ik0, ik1);          // k_idx = split[0]
      tf2x32(f0, f1, 0u, 1u, kp0[l], kp1[l]);    // k_proj = split[1]
      int Wm6 = Hs[l] - 6;
      int n = Wm6 * Wm6;
      int nd = n < 128 ? n : 128;
      std::vector<int> perm(n);
      std::iota(perm.begin(), perm.end(), 0);
      int rounds = (int)std::ceil(3.0 * std::log((double)n) / std::log(4294967295.0));
      uint32_t key0 = ik0, key1 = ik1;
      std::vector<uint32_t> bits(n);
      std::vector<int> ord(n), tmp(n);
      for (int r = 0; r < rounds; ++r) {
        uint32_t nk0, nk1, s0, s1;
        tf2x32(key0, key1, 0u, 0u, nk0, nk1);
        tf2x32(key0, key1, 0u, 1u, s0, s1);
        key0 = nk0; key1 = nk1;
        for (int tt = 0; tt < n; ++tt) {
          uint32_t o0, o1;
          tf2x32(s0, s1, 0u, (uint32_t)tt, o0, o1);
          bits[tt] = o0 ^ o1;
        }
        std::iota(ord.begin(), ord.end(), 0);
        std::stable_sort(ord.begin(), ord.end(),
                         [&](int A, int B) { return bits[A] < bits[B]; });
        for (int i2 = 0; i2 < n; ++i2) tmp[i2] = perm[ord[i2]];
        perm.swap(tmp);
      }
      for (int d = 0; d < 128; ++d) {
        int vv = (d < nd) ? perm[d] : 0;
        rcs[l].rc[d] = ((uint32_t)(vv / Wm6) << 16) | (uint32_t)(vv % Wm6);
      }
    }
  }
};
static const HostTables g_tbl;

__device__ inline float erfinv_f(float x) {
  float w = -log1pf(-x * x);
  float p;
  if (w < 5.0f) {
    w = w - 2.5f;
    p = 2.81022636e-08f;
    p = fmaf(p, w, 3.43273939e-07f);
    p = fmaf(p, w, -3.5233877e-06f);
    p = fmaf(p, w, -4.39150654e-06f);
    p = fmaf(p, w, 0.00021858087f);
    p = fmaf(p, w, -0.00125372503f);
    p = fmaf(p, w, -0.00417768164f);
    p = fmaf(p, w, 0.246640727f);
    p = fmaf(p, w, 1.50140941f);
  } else {
    w = sqrtf(w) - 3.0f;
    p = -0.000200214257f;
    p = fmaf(p, w, 0.000100950558f);
    p = fmaf(p, w, 0.00134934322f);
    p = fmaf(p, w, -0.00367342844f);
    p = fmaf(p, w, 0.00573950773f);
    p = fmaf(p, w, -0.0076224613f);
    p = fmaf(p, w, 0.00943887047f);
    p = fmaf(p, w, 1.00167406f);
    p = fmaf(p, w, 2.83297682f);
  }
  return p * x;
}

__device__ inline float bits_to_normal(uint32_t b) {
  union { uint32_t u; float f; } cv;
  cv.u = (b >> 9) | 0x3f800000u;
  float f = cv.f - 1.0f;
  const float lo = -0.99999994f;
  const float span = 1.0f - lo;
  float u = fmaxf(lo, __fadd_rn(__fmul_rn(f, span), lo));
  return 1.41421356237f * erfinv_f(u);
}

// pack float -> (bf16_hi | bf16_lo<<16), both RNE; v ~= hi + lo to ~16 mant bits
__device__ inline uint32_t pack_bf16x2(float v) {
  uint32_t u = __float_as_uint(v);
  uint32_t hi = (u + 0x7fffu + ((u >> 16) & 1u)) >> 16;
  float r = v - __uint_as_float(hi << 16);
  uint32_t ul = __float_as_uint(r);
  uint32_t lo = (ul + 0x7fffu + ((ul >> 16) & 1u)) >> 16;
  return hi | (lo << 16);
}

// ---- kernels ----

// LDS-tiled separable 5x5 binomial downsample (stride 2, zero-pad 2).
__global__ __launch_bounds__(256) void down_kernel(
    const float* __restrict__ inX, float* __restrict__ outX,
    const float* __restrict__ inY, float* __restrict__ outY,
    int H, int ltr, int lgW) {
  __shared__ __align__(16) float si[2816];  // max 11*256 (L1)
  __shared__ float hb[1408];                // max 11*128 (L1)
  int W = 1 << lgW;
  int lgWo = lgW - 1;
  int Wo = W >> 1, Ho = H >> 1;
  int TR = 1 << ltr;
  int lgnby = lgWo - ltr;                   // nby = Ho/TR (pow2)
  int nby = 1 << lgnby;
  int per = 384 << lgnby;
  int bid = blockIdx.x;
  const float* in = inX; float* out = outX;
  if (bid >= per) { bid -= per; in = inY; out = outY; }
  int bc = bid >> lgnby;
  int by = bid & (nby - 1);
  int oy0 = by << ltr;
  int rows = 2 * TR + 3;
  int y0 = 2 * oy0 - 2;
  const float* src = in + (size_t)bc * H * W;
  int t = threadIdx.x;

  int nf4 = (rows << lgW) >> 2;
  for (int i = t; i < nf4; i += 256) {
    int fi = i << 2;
    int r = fi >> lgW, x = fi & (W - 1);
    int y = y0 + r;
    float4 v = (y >= 0 && y < H) ? *(const float4*)(src + ((size_t)y << lgW) + x)
                                 : make_float4(0.f, 0.f, 0.f, 0.f);
    *(float4*)(si + fi) = v;
  }
  __syncthreads();

  int nh = rows << lgWo;
  for (int i = t; i < nh; i += 256) {
    int r = i >> lgWo, ox = i & (Wo - 1);
    const float* rp = si + (r << lgW);
    int xb = 2 * ox;
    float s = 0.375f * rp[xb] + 0.25f * rp[xb + 1];
    if (ox >= 1) s += 0.0625f * rp[xb - 2] + 0.25f * rp[xb - 1];
    if (xb + 2 < W) s += 0.0625f * rp[xb + 2];
    hb[i] = s;
  }
  __syncthreads();

  int no = TR << lgWo;
  float* dst = out + (size_t)bc * Ho * Wo;
  for (int i = t; i < no; i += 256) {
    int r = i >> lgWo, ox = i & (Wo - 1);
    const float* cp = hb + ((2 * r) << lgWo) + ox;
    float s = 0.0625f * cp[0] + 0.25f * cp[Wo] + 0.375f * cp[2 * Wo] +
              0.25f * cp[3 * Wo] + 0.0625f * cp[4 * Wo];
    dst[((size_t)(oy0 + r) << lgWo) + ox] = s;
  }
}

// all 5 levels' random projection bits in one dispatch; block 0 also zeroes misc
__global__ void randgen_kernel(float* __restrict__ rnd, Keys ks,
                               float* __restrict__ misc) {
  int t = blockIdx.x * 256 + threadIdx.x;   // 1470 blocks = 376320 = 5*75264
  if (blockIdx.x == 0 && threadIdx.x < 128) misc[threadIdx.x] = 0.f;
  const int per = 75264;                    // 147*512
  int l = t / per;
  int tt = t - l * per;
  if (l < 5) {
    uint32_t o0, o1;
    tf2x32(ks.a[l], ks.b[l], 0u, (uint32_t)tt, o0, o1);
    rnd[l * per + tt] = bits_to_normal(o0 ^ o1);
  }
}

// per-(level,column) rnd statistics: inv std (ddof=1) of the 147 entries,
// plus per-channel column sums S_c[j] (for the gemm-folded bias).
__global__ void rndstats_kernel(const float* __restrict__ rnd,
                                float* __restrict__ inv1s,
                                float* __restrict__ scS) {
  int t = blockIdx.x * 256 + threadIdx.x;   // 2560 = 5 levels x 512 cols
  int l = t >> 9, j = t & 511;
  const float* rp = rnd + (size_t)l * 75264 + j;
  float sum = 0.f, q = 0.f;
  float sc[3];
#pragma unroll
  for (int c = 0; c < 3; ++c) {
    float s = 0.f;
    for (int ff = 0; ff < 49; ++ff) {
      float v = rp[(c * 49 + ff) * 512];
      s += v; q = fmaf(v, v, q);
    }
    sc[c] = s; sum += s;
  }
  float mean = sum * (1.f / 147.f);
  float var = (q - 147.f * mean * mean) * (1.f / 146.f);
  inv1s[t] = 1.f / sqrtf(var);
#pragma unroll
  for (int c = 0; c < 3; ++c) scS[(size_t)l * 1536 + c * 512 + j] = sc[c];
}

// Laplacian 7-row body; PAR = cb&1 so all q indices are compile-time.
template <int PAR>
__device__ __forceinline__ void lap7(
    const float* __restrict__ gc, const float (&q0)[6], const float (&q1)[6],
    const float (&q2)[6], int cb, int H, float rw0, float rw2,
    uint32_t* __restrict__ po, float& sum7, float& sq7) {
#pragma unroll
  for (int v = 0; v < 7; ++v) {
    const int iw = ((v + PAR) >> 1) + 1;
    const int xo = PAR ^ (v & 1);
    int x = cb + v;
    float val = gc[x];
    float cw0 = (x >= 2) ? (xo ? 0.0625f : 0.3125f) : 0.f;
    float cw2 = (x <= H - 3) ? (xo ? 0.3125f : 0.0625f) : 0.f;
    float s0 = cw0 * q0[iw - 1] + 0.625f * q0[iw] + cw2 * q0[iw + 1];
    float s1 = cw0 * q1[iw - 1] + 0.625f * q1[iw] + cw2 * q1[iw + 1];
    float s2 = cw0 * q2[iw - 1] + 0.625f * q2[iw] + cw2 * q2[iw + 1];
    val -= rw0 * s0 + 0.625f * s1 + rw2 * s2;
    po[v] = pack_bf16x2(val);
    sum7 += val; sq7 = fmaf(val, val, sq7);
  }
}

// extract, row-granular: unit = (row, k) with k<21 -> (c = k/7, u = k%7)
// handling 7 patch elements; k==21 fills pad cols 147-159.
__global__ __launch_bounds__(256) void extract_kernel(
    const float* __restrict__ g1, const float* __restrict__ gn1,
    uint32_t* __restrict__ p1g, float* __restrict__ part1,
    const float* __restrict__ g2, const float* __restrict__ gn2,
    uint32_t* __restrict__ p2g, float* __restrict__ part2,
    RC rcs, int H, int nd, int useLap, int M) {
  __shared__ float ls[6];
  if (threadIdx.x < 6) ls[threadIdx.x] = 0.f;
  __syncthreads();
  int half = (blockIdx.x >= EXB) ? 1 : 0;
  int bid = blockIdx.x - half * EXB;
  const float* g = half ? g2 : g1;
  const float* gn = half ? gn2 : gn1;
  uint32_t* p = half ? p2g : p1g;
  float* part = half ? part2 : part1;
  int totalU = M * 22;
  for (int unit = bid * 256 + threadIdx.x; unit < totalU; unit += EXB * 256) {
    int row = unit / 22;
    int k = unit - row * 22;
    if (k < 21) {
      int d, b;
      if (nd == 128) { d = row & 127; b = row >> 7; }
      else { b = row / nd; d = row - b * nd; }
      unsigned rc = rcs.rc[d];
      int r = (int)(rc >> 16);
      int cb = (int)(rc & 0xffffu);
      int c = k / 7, u = k - (k / 7) * 7;
      int y = r + u;
      const float* gc = g + ((size_t)(b * 3 + c)) * H * H + (size_t)y * H;
      uint32_t* po = p + (size_t)row * 160 + c * 49 + u * 7;
      float sum7 = 0.f, sq7 = 0.f;
      if (useLap) {
        int H2 = H >> 1;
        const float* gnc = gn + ((size_t)(b * 3 + c)) * H2 * H2;
        int h = y >> 1, yo = y & 1;
        float rw0 = (y >= 2) ? (yo ? 0.0625f : 0.3125f) : 0.f;
        float rw2 = (y <= H - 3) ? (yo ? 0.3125f : 0.0625f) : 0.f;
        int r0 = max(h - 1, 0), r2 = min(h + 1, H2 - 1);
        const float* R0 = gnc + (size_t)r0 * H2;
        const float* R1 = gnc + (size_t)h * H2;
        const float* R2 = gnc + (size_t)r2 * H2;
        int wb = (cb >> 1) - 1;       // may be -1; clamped loads below
        float q0[6], q1[6], q2[6];
#pragma unroll
        for (int kk = 0; kk < 6; ++kk) {
          int a = wb + kk;
          a = a < 0 ? 0 : (a > H2 - 1 ? H2 - 1 : a);
          q0[kk] = R0[a]; q1[kk] = R1[a]; q2[kk] = R2[a];
        }
        if (cb & 1) lap7<1>(gc, q0, q1, q2, cb, H, rw0, rw2, po, sum7, sq7);
        else        lap7<0>(gc, q0, q1, q2, cb, H, rw0, rw2, po, sum7, sq7);
      } else {
#pragma unroll
        for (int v = 0; v < 7; ++v) {
          float val = gc[cb + v];
          po[v] = pack_bf16x2(val);
          sum7 += val; sq7 = fmaf(val, val, sq7);
        }
      }
      atomicAdd(&ls[c], sum7);
      atomicAdd(&ls[3 + c], sq7);
    } else {
      uint32_t* po = p + (size_t)row * 160 + 147;
      po[0] = 0x3F80u; po[1] = 0x3F80u; po[2] = 0x3F80u;
#pragma unroll
      for (int kk = 3; kk < 13; ++kk) po[kk] = 0u;
    }
  }
  __syncthreads();
  if (threadIdx.x < 6) part[bid * 6 + threadIdx.x] = ls[threadIdx.x];
}

// reduce EXB-block partials of both sides -> redg[12] in global.
__global__ void redpart_kernel(const float* __restrict__ part1,
                               const float* __restrict__ part2,
                               float* __restrict__ redg) {
  __shared__ float red[12];
  int tid = threadIdx.x;
  if (tid < 12) red[tid] = 0.f;
  __syncthreads();
  if (tid < 192) {
    int k = tid >> 4, r0 = tid & 15;        // 12 groups x 16 threads; 1024%16==0
    const float* src = (k < 6) ? part1 : part2;
    int kk = (k < 6) ? k : k - 6;
    float ssum = 0.f;
    for (int r = r0; r < EXB; r += 16) ssum += src[r * 6 + kk];
    atomicAdd(&red[k], ssum);
  }
  __syncthreads();
  if (tid < 12) redg[tid] = red[tid];
}

// B build, TRANSPOSED + packed: Bt[j][f] (512 x 160) = bf16-pair of W.
__global__ void prep_kernel(
    const float* __restrict__ rnd, const float* __restrict__ inv1v,
    const float* __restrict__ scS, const float* __restrict__ redg,
    uint32_t* __restrict__ Bt1, uint32_t* __restrict__ Bt2, float Np) {
  int j = blockIdx.x;
  int f = threadIdx.x;
  if (f >= 160) return;
  int o = j * 160 + f;
  if (f >= 150) { Bt1[o] = 0u; Bt2[o] = 0u; return; }
  int c = (f < 147) ? (f / 49) : (f - 147);
  float m1 = redg[c] / Np;
  float v1 = (redg[3 + c] - Np * m1 * m1) / (Np - 1.f);
  float i1 = 1.f / (sqrtf(fmaxf(v1, 0.f)) + 1e-8f);
  float m2 = redg[6 + c] / Np;
  float v2 = (redg[9 + c] - Np * m2 * m2) / (Np - 1.f);
  float i2 = 1.f / (sqrtf(fmaxf(v2, 0.f)) + 1e-8f);
  float inv1 = inv1v[j];
  float w1, w2;
  if (f < 147) {
    float rv = rnd[f * 512 + j] * inv1;
    w1 = rv * i1; w2 = rv * i2;
  } else {
    float s = scS[c * 512 + j] * inv1;
    w1 = -m1 * i1 * s; w2 = -m2 * i2 * s;
  }
  Bt1[o] = pack_bf16x2(w1);
  Bt2[o] = pack_bf16x2(w2);
}

// C[n][m] col-major (stride 16384) = A[M][160] * B[160][512], bias folded.
// MFMA bf16-split: C = Ah.Bh + Ah.Bl + Al.Bh.
#define GBM 128
#define GBN 128
__global__ __launch_bounds__(256, 3) void gemm_kernel(
    const uint32_t* __restrict__ A1, const uint32_t* __restrict__ Bt1,
    const uint32_t* __restrict__ A2, const uint32_t* __restrict__ Bt2,
    float* __restrict__ C1, float* __restrict__ C2, int M) {
  __shared__ __align__(16) unsigned short AhS[128 * 40];
  __shared__ __align__(16) unsigned short AlS[128 * 40];
  __shared__ __align__(16) unsigned short BhS[128 * 40];
  __shared__ __align__(16) unsigned short BlS[128 * 40];
  int z = blockIdx.z;
  const uint32_t* A = z ? A2 : A1;
  const uint32_t* Bt = z ? Bt2 : Bt1;
  float* C = z ? C2 : C1;
  int bm = blockIdx.x * GBM;
  int bn = blockIdx.y * GBN;
  int tid = threadIdx.x;
  int lane = tid & 63;
  int wid = tid >> 6;
  int wm = wid & 1, wn = wid >> 1;
  int fr = lane & 15;
  int kb = (lane >> 4) << 3;            // k-offset of this lane's 8 elems
  f32x4 acc[4][4];
#pragma unroll
  for (int i = 0; i < 4; ++i)
#pragma unroll
    for (int j = 0; j < 4; ++j) acc[i][j] = (f32x4){0.f, 0.f, 0.f, 0.f};

  for (int k0 = 0; k0 < 160; k0 += 32) {
#pragma unroll
    for (int i = 0; i < 4; ++i) {
      int e = tid * 16 + i * 4;
      int m = e >> 5, kk = e & 31;
      uint4 v = *(const uint4*)(A + (size_t)(bm + m) * 160 + k0 + kk);
      us4 h = {(unsigned short)v.x, (unsigned short)v.y,
               (unsigned short)v.z, (unsigned short)v.w};
      us4 l = {(unsigned short)(v.x >> 16), (unsigned short)(v.y >> 16),
               (unsigned short)(v.z >> 16), (unsigned short)(v.w >> 16)};
      *(us4*)(AhS + m * 40 + kk) = h;
      *(us4*)(AlS + m * 40 + kk) = l;
      uint4 w = *(const uint4*)(Bt + (size_t)(bn + m) * 160 + k0 + kk);
      us4 wh = {(unsigned short)w.x, (unsigned short)w.y,
                (unsigned short)w.z, (unsigned short)w.w};
      us4 wl = {(unsigned short)(w.x >> 16), (unsigned short)(w.y >> 16),
                (unsigned short)(w.z >> 16), (unsigned short)(w.w >> 16)};
      *(us4*)(BhS + m * 40 + kk) = wh;
      *(us4*)(BlS + m * 40 + kk) = wl;
    }
    __syncthreads();
    bf16x8 ah[4], al[4], bh[4], bl[4];
#pragma unroll
    for (int mt = 0; mt < 4; ++mt) {
      int m = wm * 64 + mt * 16 + fr;
      ah[mt] = *(const bf16x8*)(AhS + m * 40 + kb);
      al[mt] = *(const bf16x8*)(AlS + m * 40 + kb);
    }
#pragma unroll
    for (int nt = 0; nt < 4; ++nt) {
      int n = wn * 64 + nt * 16 + fr;
      bh[nt] = *(const bf16x8*)(BhS + n * 40 + kb);
      bl[nt] = *(const bf16x8*)(BlS + n * 40 + kb);
    }
#pragma unroll
    for (int mt = 0; mt < 4; ++mt)
#pragma unroll
      for (int nt = 0; nt < 4; ++nt) {
        acc[mt][nt] = __builtin_amdgcn_mfma_f32_16x16x32_bf16(
            ah[mt], bh[nt], acc[mt][nt], 0, 0, 0);
        acc[mt][nt] = __builtin_amdgcn_mfma_f32_16x16x32_bf16(
            ah[mt], bl[nt], acc[mt][nt], 0, 0, 0);
        acc[mt][nt] = __builtin_amdgcn_mfma_f32_16x16x32_bf16(
            al[mt], bh[nt], acc[mt][nt], 0, 0, 0);
      }
    __syncthreads();
  }
  // C/D layout: col = lane&15, row = 4*(lane>>4) + reg  [m89 verified]
  int mrow = (lane >> 4) << 2;
#pragma unroll
  for (int mt = 0; mt < 4; ++mt)
#pragma unroll
    for (int nt = 0; nt < 4; ++nt) {
      int n = bn + wn * 64 + nt * 16 + fr;
      int m = bm + wm * 64 + mt * 16 + mrow;
      f32x4 v = acc[mt][nt];
      *(float4*)(C + (size_t)n * 16384 + m) = make_float4(v[0], v[1], v[2], v[3]);
    }
}

// ---- merge-path sort + diff, 32 elems/thread (bank-swizzled LDS) ----
__device__ inline int corank(const float* __restrict__ s, int pb, int L, int so) {
  int lo = so - L; lo = lo < 0 ? 0 : lo;
  int hi = so < L ? so : L;
  while (lo < hi) {
    int mid = (lo + hi) >> 1;
    float a = s[SIDX(pb + mid)];
    float b = s[SIDX(pb + L + so - 1 - mid)];
    if (a < b) lo = mid + 1; else hi = mid;
  }
  return lo;
}

__device__ __forceinline__ void merge_round(float (&v)[32], float* __restrict__ s,
                                            int t, int bi, int L, bool crosswave) {
  int sw = ((bi >> 5) ^ (bi >> 10)) & 31;   // constant per thread
#pragma unroll
  for (int q = 0; q < 32; ++q) s[(bi + q) ^ sw] = v[q];
  if (crosswave) __syncthreads();
  else __builtin_amdgcn_wave_barrier();
  int pb = bi & ~(2 * L - 1);
  int so = bi - pb;
  int i0 = corank(s, pb, L, so);
  int nxt = __shfl_down(i0, 1, 64);   // lane t+1's i0 == our i1
  int i1;
  if (((so + 32) & (2 * L - 1)) == 0) i1 = L;              // last window slot
  else if (crosswave && (t & 63) == 63) i1 = corank(s, pb, L, so + 32);
  else i1 = nxt;
  int na = i1 - i0;
  int j1 = so + 32 - i1;
#pragma unroll
  for (int q = 0; q < 32; ++q) {
    int idx = (q < na) ? (pb + i0 + q)
                       : (pb + L + j1 - 1 - (q - na));
    v[q] = s[SIDX(idx)];
  }
#pragma unroll
  for (int j = 16; j >= 1; j >>= 1) {
#pragma unroll
    for (int q = 0; q < 32; ++q) {
      if ((q & j) == 0) {
        float a = v[q], b = v[q | j];
        v[q] = fminf(a, b);
        v[q | j] = fmaxf(a, b);
      }
    }
  }
  if (crosswave) __syncthreads();
}

__device__ __forceinline__ void mergesort_col(float (&v)[32], float* __restrict__ s,
                                              int t, int bi) {
  for (int L = 32; L <= 1024; L <<= 1) merge_round(v, s, t, bi, L, false);
  for (int L = 2048; L <= 8192; L <<= 1) merge_round(v, s, t, bi, L, true);
}

__global__ __launch_bounds__(512, 2) void sortdiff_kernel(
    const float* __restrict__ proj1, const float* __restrict__ proj2,
    float* __restrict__ sum, int m) {
  __shared__ float s[16384];
  int t = threadIdx.x;
  int col = blockIdx.x;  // 0..511
  const float INF = __builtin_huge_valf();
  float va[32], vb[32];
  int bi = t << 5;

  const float* pa = proj1 + (size_t)col * 16384;
  const float* pbp = proj2 + (size_t)col * 16384;
  if (bi < m) {
#pragma unroll
    for (int i = 0; i < 8; ++i) {
      float4 A4 = *(const float4*)(pa + bi + i * 4);
      va[i * 4 + 0] = A4.x; va[i * 4 + 1] = A4.y;
      va[i * 4 + 2] = A4.z; va[i * 4 + 3] = A4.w;
      float4 B4 = *(const float4*)(pbp + bi + i * 4);
      vb[i * 4 + 0] = B4.x; vb[i * 4 + 1] = B4.y;
      vb[i * 4 + 2] = B4.z; vb[i * 4 + 3] = B4.w;
    }
  } else {
#pragma unroll
    for (int r = 0; r < 32; ++r) { va[r] = INF; vb[r] = INF; }
  }

  // ---- in-thread bitonic-32 sort, both columns interleaved (2x ILP)
#pragma unroll
  for (int k = 2; k <= 32; k <<= 1) {
#pragma unroll
    for (int j = k >> 1; j >= 1; j >>= 1) {
#pragma unroll
      for (int r = 0; r < 32; ++r) {
        if ((r & j) == 0) {
          bool up = ((r & k) == 0);   // k=32: always true for r<32
          float a0 = va[r], b0 = va[r | j];
          float lo0 = fminf(a0, b0), hi0 = fmaxf(a0, b0);
          va[r] = up ? lo0 : hi0;
          va[r | j] = up ? hi0 : lo0;
          float a1 = vb[r], b1 = vb[r | j];
          float lo1 = fminf(a1, b1), hi1 = fmaxf(a1, b1);
          vb[r] = up ? lo1 : hi1;
          vb[r | j] = up ? hi1 : lo1;
        }
      }
    }
  }

  // column A: 9 merge-path rounds; result stays in va. exits synced.
  mergesort_col(va, s, t, bi);
  // column B: reuse LDS; result lands in vb.
  mergesort_col(vb, s, t, bi);

  float acc = 0.f;
  if (bi < m) {
#pragma unroll
    for (int q = 0; q < 32; ++q) acc += fabsf(va[q] - vb[q]);
  }

#pragma unroll
  for (int o = 32; o > 0; o >>= 1) acc += __shfl_down(acc, o, 64);
  if ((t & 63) == 0) s[t >> 6] = acc;
  __syncthreads();
  if (t == 0) {
    float tot = 0.f;
    for (int i = 0; i < 8; ++i) tot += s[i];
    atomicAdd(sum, tot);
  }
}

__global__ void final_kernel(const float* __restrict__ sums, float* __restrict__ out) {
  float r = sums[0] * (1.f / 8388608.f) + sums[1] * (1.f / 8388608.f) +
            sums[2] * (1.f / 8388608.f) + sums[3] * (1.f / 8388608.f) +
            sums[4] * (1.f / 6553600.f);
  out[0] = r * (1000.f / 5.f);
}

// ---------------------------------------------------------------------------

extern "C" void kernel_launch(void* const* d_in, const int* in_sizes, int n_in,
                              void* d_out, int out_size, void* d_ws, size_t ws_size,
                              hipStream_t stream) {
  const float* xin = (const float*)d_in[0];
  const float* yin = (const float*)d_in[1];
  float* out = (float*)d_out;

  char* base = (char*)d_ws;
  size_t off = 0;
  auto alloc = [&](size_t nfloats) -> float* {
    float* p = (float*)(base + off);
    off += ((nfloats * 4) + 255) & ~(size_t)255;
    return p;
  };
  float* gX[5];
  float* gY[5];
  gX[0] = (float*)xin;
  gY[0] = (float*)yin;
  gX[1] = alloc(6291456); gX[2] = alloc(1572864); gX[3] = alloc(393216); gX[4] = alloc(98304);
  gY[1] = alloc(6291456); gY[2] = alloc(1572864); gY[3] = alloc(393216); gY[4] = alloc(98304);
  uint32_t* p1 = (uint32_t*)alloc((size_t)16384 * 160);
  uint32_t* p2 = (uint32_t*)alloc((size_t)16384 * 160);
  float* rnd = alloc((size_t)5 * 75264);
  float* inv1s = alloc(5 * 512);
  float* scS = alloc((size_t)5 * 1536);
  float* redg = alloc(16);
  uint32_t* Bt1 = (uint32_t*)alloc(160 * 512);
  uint32_t* Bt2 = (uint32_t*)alloc(160 * 512);
  float* proj1 = alloc((size_t)16384 * 512);
  float* proj2 = alloc((size_t)16384 * 512);
  float* part1 = alloc(EXB * 6);
  float* part2 = alloc(EXB * 6);
  float* misc = alloc(128);

  static const int Hs[5] = {256, 128, 64, 32, 16};

  Keys ks;
  for (int l = 0; l < 5; ++l) { ks.a[l] = g_tbl.kp0[l]; ks.b[l] = g_tbl.kp1[l]; }
  randgen_kernel<<<1470, 256, 0, stream>>>(rnd, ks, misc);
  rndstats_kernel<<<10, 256, 0, stream>>>(rnd, inv1s, scS);

  // fused X+Y separable pyramid downsampling
  down_kernel<<<2 * 384 * 32, 256, 0, stream>>>(xin, gX[1], yin, gY[1], 256, 2, 8);
  down_kernel<<<2 * 384 * 8, 256, 0, stream>>>(gX[1], gX[2], gY[1], gY[2], 128, 3, 7);
  down_kernel<<<2 * 384 * 2, 256, 0, stream>>>(gX[2], gX[3], gY[2], gY[3], 64, 4, 6);
  down_kernel<<<2 * 384 * 1, 256, 0, stream>>>(gX[3], gX[4], gY[3], gY[4], 32, 4, 5);

  for (int l = 0; l < 5; ++l) {
    int H = Hs[l];
    int Wm6 = H - 6;
    int n = Wm6 * Wm6;
    int nd = n < 128 ? n : 128;
    int M = 128 * nd;
    extract_kernel<<<2 * EXB, 256, 0, stream>>>(
        gX[l], (l < 4) ? gX[l + 1] : nullptr, p1, part1,
        gY[l], (l < 4) ? gY[l + 1] : nullptr, p2, part2,
        g_tbl.rcs[l], H, nd, (l < 4) ? 1 : 0, M);
    redpart_kernel<<<1, 256, 0, stream>>>(part1, part2, redg);
    prep_kernel<<<512, 192, 0, stream>>>(rnd + (size_t)l * 75264, inv1s + l * 512,
                                         scS + (size_t)l * 1536, redg, Bt1, Bt2,
                                         (float)M * 49.f);
    dim3 gg(M / 128, 4, 2);
    gemm_kernel<<<gg, 256, 0, stream>>>(p1, Bt1, p2, Bt2, proj1, proj2, M);
    sortdiff_kernel<<<512, 512, 0, stream>>>(proj1, proj2, misc + l, M);
  }
  final_kernel<<<1, 1, 0, stream>>>(misc, out);
}

// Round 16
// 1231.946 us; speedup vs baseline: 1.0978x; 1.0978x over previous
//
#include <hip/hip_runtime.h>
#include <hip/hip_bf16.h>
#include <cstdint>
#include <cmath>
#include <vector>
#include <algorithm>
#include <numeric>

// ---------------------------------------------------------------------------
// LapSWD loss. RNG = exact JAX partitionable threefry.
// R21 = R19 restored verbatim. R20's (512,2) occupancy experiment REGRESSED
// (124->148us: compiler used only 68 VGPR -- no spill existed; occupancy
// 35->22% was the real cost). Spill theory refuted; sortdiff FROZEN at
// (512,4): three structural attempts (R14 bitonic, R17 swizzle-v2, R20
// occupancy) all lost to the 124us merge-path baseline.
// R19: row-granular extract (25 loads/7 outputs). R18: MFMA bf16-split gemm.
// R17: bias fold + parallel prep. R16: 32/thr merge-path. R13: separable down.
// ---------------------------------------------------------------------------

#define SIDX(i) ((i) ^ ((((i) >> 5) ^ ((i) >> 10)) & 31))
#define EXB 1024  // extract grid per half: 1024 blocks x 256 thr, grid-stride

typedef __attribute__((ext_vector_type(8))) short bf16x8;
typedef __attribute__((ext_vector_type(4))) float f32x4;
typedef __attribute__((ext_vector_type(4))) unsigned short us4;

struct RC { unsigned int rc[128]; };
struct Keys { uint32_t a[5]; uint32_t b[5]; };

// ---- threefry2x32 block cipher, exact JAX/XLA schedule ----
__host__ __device__ inline void tf2x32(uint32_t k0, uint32_t k1,
                                       uint32_t x0, uint32_t x1,
                                       uint32_t& o0, uint32_t& o1) {
  uint32_t k2 = k0 ^ k1 ^ 0x1BD11BDAu;
  x0 += k0; x1 += k1;
#define TFR(r) { x0 += x1; x1 = (x1 << r) | (x1 >> (32 - r)); x1 ^= x0; }
  TFR(13) TFR(15) TFR(26) TFR(6)   x0 += k1; x1 += k2 + 1u;
  TFR(17) TFR(29) TFR(16) TFR(24)  x0 += k2; x1 += k0 + 2u;
  TFR(13) TFR(15) TFR(26) TFR(6)   x0 += k0; x1 += k1 + 3u;
  TFR(17) TFR(29) TFR(16) TFR(24)  x0 += k1; x1 += k2 + 4u;
  TFR(13) TFR(15) TFR(26) TFR(6)   x0 += k2; x1 += k0 + 5u;
#undef TFR
  o0 = x0; o1 = x1;
}

// ---- host tables (pure constants; computed once at library load) ----
struct HostTables {
  RC rcs[5];
  uint32_t kp0[5], kp1[5];
  HostTables() {
    static const int Hs[5] = {256, 128, 64, 32, 16};
    for (int l = 0; l < 5; ++l) {
      uint32_t f0, f1;
      tf2x32(0u, 42u, 0u, (uint32_t)l, f0, f1);  // fold_in(key(42), l)
      uint32_t ik0, ik1;
      tf2x32(f0, f1, 0u, 0u, ik0, ik1);          // k_idx = split[0]
      tf2x32(f0, f1, 0u, 1u, kp0[l], kp1[l]);    // k_proj = split[1]
      int Wm6 = Hs[l] - 6;
      int n = Wm6 * Wm6;
      int nd = n < 128 ? n : 128;
      std::vector<int> perm(n);
      std::iota(perm.begin(), perm.end(), 0);
      int rounds = (int)std::ceil(3.0 * std::log((double)n) / std::log(4294967295.0));
      uint32_t key0 = ik0, key1 = ik1;
      std::vector<uint32_t> bits(n);
      std::vector<int> ord(n), tmp(n);
      for (int r = 0; r < rounds; ++r) {
        uint32_t nk0, nk1, s0, s1;
        tf2x32(key0, key1, 0u, 0u, nk0, nk1);
        tf2x32(key0, key1, 0u, 1u, s0, s1);
        key0 = nk0; key1 = nk1;
        for (int tt = 0; tt < n; ++tt) {
          uint32_t o0, o1;
          tf2x32(s0, s1, 0u, (uint32_t)tt, o0, o1);
          bits[tt] = o0 ^ o1;
        }
        std::iota(ord.begin(), ord.end(), 0);
        std::stable_sort(ord.begin(), ord.end(),
                         [&](int A, int B) { return bits[A] < bits[B]; });
        for (int i2 = 0; i2 < n; ++i2) tmp[i2] = perm[ord[i2]];
        perm.swap(tmp);
      }
      for (int d = 0; d < 128; ++d) {
        int vv = (d < nd) ? perm[d] : 0;
        rcs[l].rc[d] = ((uint32_t)(vv / Wm6) << 16) | (uint32_t)(vv % Wm6);
      }
    }
  }
};
static const HostTables g_tbl;

__device__ inline float erfinv_f(float x) {
  float w = -log1pf(-x * x);
  float p;
  if (w < 5.0f) {
    w = w - 2.5f;
    p = 2.81022636e-08f;
    p = fmaf(p, w, 3.43273939e-07f);
    p = fmaf(p, w, -3.5233877e-06f);
    p = fmaf(p, w, -4.39150654e-06f);
    p = fmaf(p, w, 0.00021858087f);
    p = fmaf(p, w, -0.00125372503f);
    p = fmaf(p, w, -0.00417768164f);
    p = fmaf(p, w, 0.246640727f);
    p = fmaf(p, w, 1.50140941f);
  } else {
    w = sqrtf(w) - 3.0f;
    p = -0.000200214257f;
    p = fmaf(p, w, 0.000100950558f);
    p = fmaf(p, w, 0.00134934322f);
    p = fmaf(p, w, -0.00367342844f);
    p = fmaf(p, w, 0.00573950773f);
    p = fmaf(p, w, -0.0076224613f);
    p = fmaf(p, w, 0.00943887047f);
    p = fmaf(p, w, 1.00167406f);
    p = fmaf(p, w, 2.83297682f);
  }
  return p * x;
}

__device__ inline float bits_to_normal(uint32_t b) {
  union { uint32_t u; float f; } cv;
  cv.u = (b >> 9) | 0x3f800000u;
  float f = cv.f - 1.0f;
  const float lo = -0.99999994f;
  const float span = 1.0f - lo;
  float u = fmaxf(lo, __fadd_rn(__fmul_rn(f, span), lo));
  return 1.41421356237f * erfinv_f(u);
}

// pack float -> (bf16_hi | bf16_lo<<16), both RNE; v ~= hi + lo to ~16 mant bits
__device__ inline uint32_t pack_bf16x2(float v) {
  uint32_t u = __float_as_uint(v);
  uint32_t hi = (u + 0x7fffu + ((u >> 16) & 1u)) >> 16;
  float r = v - __uint_as_float(hi << 16);
  uint32_t ul = __float_as_uint(r);
  uint32_t lo = (ul + 0x7fffu + ((ul >> 16) & 1u)) >> 16;
  return hi | (lo << 16);
}

// ---- kernels ----

// LDS-tiled separable 5x5 binomial downsample (stride 2, zero-pad 2).
__global__ __launch_bounds__(256) void down_kernel(
    const float* __restrict__ inX, float* __restrict__ outX,
    const float* __restrict__ inY, float* __restrict__ outY,
    int H, int ltr, int lgW) {
  __shared__ __align__(16) float si[2816];  // max 11*256 (L1)
  __shared__ float hb[1408];                // max 11*128 (L1)
  int W = 1 << lgW;
  int lgWo = lgW - 1;
  int Wo = W >> 1, Ho = H >> 1;
  int TR = 1 << ltr;
  int lgnby = lgWo - ltr;                   // nby = Ho/TR (pow2)
  int nby = 1 << lgnby;
  int per = 384 << lgnby;
  int bid = blockIdx.x;
  const float* in = inX; float* out = outX;
  if (bid >= per) { bid -= per; in = inY; out = outY; }
  int bc = bid >> lgnby;
  int by = bid & (nby - 1);
  int oy0 = by << ltr;
  int rows = 2 * TR + 3;
  int y0 = 2 * oy0 - 2;
  const float* src = in + (size_t)bc * H * W;
  int t = threadIdx.x;

  int nf4 = (rows << lgW) >> 2;
  for (int i = t; i < nf4; i += 256) {
    int fi = i << 2;
    int r = fi >> lgW, x = fi & (W - 1);
    int y = y0 + r;
    float4 v = (y >= 0 && y < H) ? *(const float4*)(src + ((size_t)y << lgW) + x)
                                 : make_float4(0.f, 0.f, 0.f, 0.f);
    *(float4*)(si + fi) = v;
  }
  __syncthreads();

  int nh = rows << lgWo;
  for (int i = t; i < nh; i += 256) {
    int r = i >> lgWo, ox = i & (Wo - 1);
    const float* rp = si + (r << lgW);
    int xb = 2 * ox;
    float s = 0.375f * rp[xb] + 0.25f * rp[xb + 1];
    if (ox >= 1) s += 0.0625f * rp[xb - 2] + 0.25f * rp[xb - 1];
    if (xb + 2 < W) s += 0.0625f * rp[xb + 2];
    hb[i] = s;
  }
  __syncthreads();

  int no = TR << lgWo;
  float* dst = out + (size_t)bc * Ho * Wo;
  for (int i = t; i < no; i += 256) {
    int r = i >> lgWo, ox = i & (Wo - 1);
    const float* cp = hb + ((2 * r) << lgWo) + ox;
    float s = 0.0625f * cp[0] + 0.25f * cp[Wo] + 0.375f * cp[2 * Wo] +
              0.25f * cp[3 * Wo] + 0.0625f * cp[4 * Wo];
    dst[((size_t)(oy0 + r) << lgWo) + ox] = s;
  }
}

// all 5 levels' random projection bits in one dispatch; block 0 also zeroes misc
__global__ void randgen_kernel(float* __restrict__ rnd, Keys ks,
                               float* __restrict__ misc) {
  int t = blockIdx.x * 256 + threadIdx.x;   // 1470 blocks = 376320 = 5*75264
  if (blockIdx.x == 0 && threadIdx.x < 128) misc[threadIdx.x] = 0.f;
  const int per = 75264;                    // 147*512
  int l = t / per;
  int tt = t - l * per;
  if (l < 5) {
    uint32_t o0, o1;
    tf2x32(ks.a[l], ks.b[l], 0u, (uint32_t)tt, o0, o1);
    rnd[l * per + tt] = bits_to_normal(o0 ^ o1);
  }
}

// per-(level,column) rnd statistics: inv std (ddof=1) of the 147 entries,
// plus per-channel column sums S_c[j] (for the gemm-folded bias).
__global__ void rndstats_kernel(const float* __restrict__ rnd,
                                float* __restrict__ inv1s,
                                float* __restrict__ scS) {
  int t = blockIdx.x * 256 + threadIdx.x;   // 2560 = 5 levels x 512 cols
  int l = t >> 9, j = t & 511;
  const float* rp = rnd + (size_t)l * 75264 + j;
  float sum = 0.f, q = 0.f;
  float sc[3];
#pragma unroll
  for (int c = 0; c < 3; ++c) {
    float s = 0.f;
    for (int ff = 0; ff < 49; ++ff) {
      float v = rp[(c * 49 + ff) * 512];
      s += v; q = fmaf(v, v, q);
    }
    sc[c] = s; sum += s;
  }
  float mean = sum * (1.f / 147.f);
  float var = (q - 147.f * mean * mean) * (1.f / 146.f);
  inv1s[t] = 1.f / sqrtf(var);
#pragma unroll
  for (int c = 0; c < 3; ++c) scS[(size_t)l * 1536 + c * 512 + j] = sc[c];
}

// Laplacian 7-row body; PAR = cb&1 so all q indices are compile-time.
template <int PAR>
__device__ __forceinline__ void lap7(
    const float* __restrict__ gc, const float (&q0)[6], const float (&q1)[6],
    const float (&q2)[6], int cb, int H, float rw0, float rw2,
    uint32_t* __restrict__ po, float& sum7, float& sq7) {
#pragma unroll
  for (int v = 0; v < 7; ++v) {
    const int iw = ((v + PAR) >> 1) + 1;
    const int xo = PAR ^ (v & 1);
    int x = cb + v;
    float val = gc[x];
    float cw0 = (x >= 2) ? (xo ? 0.0625f : 0.3125f) : 0.f;
    float cw2 = (x <= H - 3) ? (xo ? 0.3125f : 0.0625f) : 0.f;
    float s0 = cw0 * q0[iw - 1] + 0.625f * q0[iw] + cw2 * q0[iw + 1];
    float s1 = cw0 * q1[iw - 1] + 0.625f * q1[iw] + cw2 * q1[iw + 1];
    float s2 = cw0 * q2[iw - 1] + 0.625f * q2[iw] + cw2 * q2[iw + 1];
    val -= rw0 * s0 + 0.625f * s1 + rw2 * s2;
    po[v] = pack_bf16x2(val);
    sum7 += val; sq7 = fmaf(val, val, sq7);
  }
}

// extract, row-granular: unit = (row, k) with k<21 -> (c = k/7, u = k%7)
// handling 7 patch elements; k==21 fills pad cols 147-159.
__global__ __launch_bounds__(256) void extract_kernel(
    const float* __restrict__ g1, const float* __restrict__ gn1,
    uint32_t* __restrict__ p1g, float* __restrict__ part1,
    const float* __restrict__ g2, const float* __restrict__ gn2,
    uint32_t* __restrict__ p2g, float* __restrict__ part2,
    RC rcs, int H, int nd, int useLap, int M) {
  __shared__ float ls[6];
  if (threadIdx.x < 6) ls[threadIdx.x] = 0.f;
  __syncthreads();
  int half = (blockIdx.x >= EXB) ? 1 : 0;
  int bid = blockIdx.x - half * EXB;
  const float* g = half ? g2 : g1;
  const float* gn = half ? gn2 : gn1;
  uint32_t* p = half ? p2g : p1g;
  float* part = half ? part2 : part1;
  int totalU = M * 22;
  for (int unit = bid * 256 + threadIdx.x; unit < totalU; unit += EXB * 256) {
    int row = unit / 22;
    int k = unit - row * 22;
    if (k < 21) {
      int d, b;
      if (nd == 128) { d = row & 127; b = row >> 7; }
      else { b = row / nd; d = row - b * nd; }
      unsigned rc = rcs.rc[d];
      int r = (int)(rc >> 16);
      int cb = (int)(rc & 0xffffu);
      int c = k / 7, u = k - (k / 7) * 7;
      int y = r + u;
      const float* gc = g + ((size_t)(b * 3 + c)) * H * H + (size_t)y * H;
      uint32_t* po = p + (size_t)row * 160 + c * 49 + u * 7;
      float sum7 = 0.f, sq7 = 0.f;
      if (useLap) {
        int H2 = H >> 1;
        const float* gnc = gn + ((size_t)(b * 3 + c)) * H2 * H2;
        int h = y >> 1, yo = y & 1;
        float rw0 = (y >= 2) ? (yo ? 0.0625f : 0.3125f) : 0.f;
        float rw2 = (y <= H - 3) ? (yo ? 0.3125f : 0.0625f) : 0.f;
        int r0 = max(h - 1, 0), r2 = min(h + 1, H2 - 1);
        const float* R0 = gnc + (size_t)r0 * H2;
        const float* R1 = gnc + (size_t)h * H2;
        const float* R2 = gnc + (size_t)r2 * H2;
        int wb = (cb >> 1) - 1;       // may be -1; clamped loads below
        float q0[6], q1[6], q2[6];
#pragma unroll
        for (int kk = 0; kk < 6; ++kk) {
          int a = wb + kk;
          a = a < 0 ? 0 : (a > H2 - 1 ? H2 - 1 : a);
          q0[kk] = R0[a]; q1[kk] = R1[a]; q2[kk] = R2[a];
        }
        if (cb & 1) lap7<1>(gc, q0, q1, q2, cb, H, rw0, rw2, po, sum7, sq7);
        else        lap7<0>(gc, q0, q1, q2, cb, H, rw0, rw2, po, sum7, sq7);
      } else {
#pragma unroll
        for (int v = 0; v < 7; ++v) {
          float val = gc[cb + v];
          po[v] = pack_bf16x2(val);
          sum7 += val; sq7 = fmaf(val, val, sq7);
        }
      }
      atomicAdd(&ls[c], sum7);
      atomicAdd(&ls[3 + c], sq7);
    } else {
      uint32_t* po = p + (size_t)row * 160 + 147;
      po[0] = 0x3F80u; po[1] = 0x3F80u; po[2] = 0x3F80u;
#pragma unroll
      for (int kk = 3; kk < 13; ++kk) po[kk] = 0u;
    }
  }
  __syncthreads();
  if (threadIdx.x < 6) part[bid * 6 + threadIdx.x] = ls[threadIdx.x];
}

// reduce EXB-block partials of both sides -> redg[12] in global.
__global__ void redpart_kernel(const float* __restrict__ part1,
                               const float* __restrict__ part2,
                               float* __restrict__ redg) {
  __shared__ float red[12];
  int tid = threadIdx.x;
  if (tid < 12) red[tid] = 0.f;
  __syncthreads();
  if (tid < 192) {
    int k = tid >> 4, r0 = tid & 15;        // 12 groups x 16 threads; 1024%16==0
    const float* src = (k < 6) ? part1 : part2;
    int kk = (k < 6) ? k : k - 6;
    float ssum = 0.f;
    for (int r = r0; r < EXB; r += 16) ssum += src[r * 6 + kk];
    atomicAdd(&red[k], ssum);
  }
  __syncthreads();
  if (tid < 12) redg[tid] = red[tid];
}

// B build, TRANSPOSED + packed: Bt[j][f] (512 x 160) = bf16-pair of W.
__global__ void prep_kernel(
    const float* __restrict__ rnd, const float* __restrict__ inv1v,
    const float* __restrict__ scS, const float* __restrict__ redg,
    uint32_t* __restrict__ Bt1, uint32_t* __restrict__ Bt2, float Np) {
  int j = blockIdx.x;
  int f = threadIdx.x;
  if (f >= 160) return;
  int o = j * 160 + f;
  if (f >= 150) { Bt1[o] = 0u; Bt2[o] = 0u; return; }
  int c = (f < 147) ? (f / 49) : (f - 147);
  float m1 = redg[c] / Np;
  float v1 = (redg[3 + c] - Np * m1 * m1) / (Np - 1.f);
  float i1 = 1.f / (sqrtf(fmaxf(v1, 0.f)) + 1e-8f);
  float m2 = redg[6 + c] / Np;
  float v2 = (redg[9 + c] - Np * m2 * m2) / (Np - 1.f);
  float i2 = 1.f / (sqrtf(fmaxf(v2, 0.f)) + 1e-8f);
  float inv1 = inv1v[j];
  float w1, w2;
  if (f < 147) {
    float rv = rnd[f * 512 + j] * inv1;
    w1 = rv * i1; w2 = rv * i2;
  } else {
    float s = scS[c * 512 + j] * inv1;
    w1 = -m1 * i1 * s; w2 = -m2 * i2 * s;
  }
  Bt1[o] = pack_bf16x2(w1);
  Bt2[o] = pack_bf16x2(w2);
}

// C[n][m] col-major (stride 16384) = A[M][160] * B[160][512], bias folded.
// MFMA bf16-split: C = Ah.Bh + Ah.Bl + Al.Bh.
#define GBM 128
#define GBN 128
__global__ __launch_bounds__(256, 3) void gemm_kernel(
    const uint32_t* __restrict__ A1, const uint32_t* __restrict__ Bt1,
    const uint32_t* __restrict__ A2, const uint32_t* __restrict__ Bt2,
    float* __restrict__ C1, float* __restrict__ C2, int M) {
  __shared__ __align__(16) unsigned short AhS[128 * 40];
  __shared__ __align__(16) unsigned short AlS[128 * 40];
  __shared__ __align__(16) unsigned short BhS[128 * 40];
  __shared__ __align__(16) unsigned short BlS[128 * 40];
  int z = blockIdx.z;
  const uint32_t* A = z ? A2 : A1;
  const uint32_t* Bt = z ? Bt2 : Bt1;
  float* C = z ? C2 : C1;
  int bm = blockIdx.x * GBM;
  int bn = blockIdx.y * GBN;
  int tid = threadIdx.x;
  int lane = tid & 63;
  int wid = tid >> 6;
  int wm = wid & 1, wn = wid >> 1;
  int fr = lane & 15;
  int kb = (lane >> 4) << 3;            // k-offset of this lane's 8 elems
  f32x4 acc[4][4];
#pragma unroll
  for (int i = 0; i < 4; ++i)
#pragma unroll
    for (int j = 0; j < 4; ++j) acc[i][j] = (f32x4){0.f, 0.f, 0.f, 0.f};

  for (int k0 = 0; k0 < 160; k0 += 32) {
#pragma unroll
    for (int i = 0; i < 4; ++i) {
      int e = tid * 16 + i * 4;
      int m = e >> 5, kk = e & 31;
      uint4 v = *(const uint4*)(A + (size_t)(bm + m) * 160 + k0 + kk);
      us4 h = {(unsigned short)v.x, (unsigned short)v.y,
               (unsigned short)v.z, (unsigned short)v.w};
      us4 l = {(unsigned short)(v.x >> 16), (unsigned short)(v.y >> 16),
               (unsigned short)(v.z >> 16), (unsigned short)(v.w >> 16)};
      *(us4*)(AhS + m * 40 + kk) = h;
      *(us4*)(AlS + m * 40 + kk) = l;
      uint4 w = *(const uint4*)(Bt + (size_t)(bn + m) * 160 + k0 + kk);
      us4 wh = {(unsigned short)w.x, (unsigned short)w.y,
                (unsigned short)w.z, (unsigned short)w.w};
      us4 wl = {(unsigned short)(w.x >> 16), (unsigned short)(w.y >> 16),
                (unsigned short)(w.z >> 16), (unsigned short)(w.w >> 16)};
      *(us4*)(BhS + m * 40 + kk) = wh;
      *(us4*)(BlS + m * 40 + kk) = wl;
    }
    __syncthreads();
    bf16x8 ah[4], al[4], bh[4], bl[4];
#pragma unroll
    for (int mt = 0; mt < 4; ++mt) {
      int m = wm * 64 + mt * 16 + fr;
      ah[mt] = *(const bf16x8*)(AhS + m * 40 + kb);
      al[mt] = *(const bf16x8*)(AlS + m * 40 + kb);
    }
#pragma unroll
    for (int nt = 0; nt < 4; ++nt) {
      int n = wn * 64 + nt * 16 + fr;
      bh[nt] = *(const bf16x8*)(BhS + n * 40 + kb);
      bl[nt] = *(const bf16x8*)(BlS + n * 40 + kb);
    }
#pragma unroll
    for (int mt = 0; mt < 4; ++mt)
#pragma unroll
      for (int nt = 0; nt < 4; ++nt) {
        acc[mt][nt] = __builtin_amdgcn_mfma_f32_16x16x32_bf16(
            ah[mt], bh[nt], acc[mt][nt], 0, 0, 0);
        acc[mt][nt] = __builtin_amdgcn_mfma_f32_16x16x32_bf16(
            ah[mt], bl[nt], acc[mt][nt], 0, 0, 0);
        acc[mt][nt] = __builtin_amdgcn_mfma_f32_16x16x32_bf16(
            al[mt], bh[nt], acc[mt][nt], 0, 0, 0);
      }
    __syncthreads();
  }
  // C/D layout: col = lane&15, row = 4*(lane>>4) + reg  [m89 verified]
  int mrow = (lane >> 4) << 2;
#pragma unroll
  for (int mt = 0; mt < 4; ++mt)
#pragma unroll
    for (int nt = 0; nt < 4; ++nt) {
      int n = bn + wn * 64 + nt * 16 + fr;
      int m = bm + wm * 64 + mt * 16 + mrow;
      f32x4 v = acc[mt][nt];
      *(float4*)(C + (size_t)n * 16384 + m) = make_float4(v[0], v[1], v[2], v[3]);
    }
}

// ---- merge-path sort + diff, 32 elems/thread (bank-swizzled LDS) ----
__device__ inline int corank(const float* __restrict__ s, int pb, int L, int so) {
  int lo = so - L; lo = lo < 0 ? 0 : lo;
  int hi = so < L ? so : L;
  while (lo < hi) {
    int mid = (lo + hi) >> 1;
    float a = s[SIDX(pb + mid)];
    float b = s[SIDX(pb + L + so - 1 - mid)];
    if (a < b) lo = mid + 1; else hi = mid;
  }
  return lo;
}

__device__ __forceinline__ void merge_round(float (&v)[32], float* __restrict__ s,
                                            int t, int bi, int L, bool crosswave) {
  int sw = ((bi >> 5) ^ (bi >> 10)) & 31;   // constant per thread
#pragma unroll
  for (int q = 0; q < 32; ++q) s[(bi + q) ^ sw] = v[q];
  if (crosswave) __syncthreads();
  else __builtin_amdgcn_wave_barrier();
  int pb = bi & ~(2 * L - 1);
  int so = bi - pb;
  int i0 = corank(s, pb, L, so);
  int nxt = __shfl_down(i0, 1, 64);   // lane t+1's i0 == our i1
  int i1;
  if (((so + 32) & (2 * L - 1)) == 0) i1 = L;              // last window slot
  else if (crosswave && (t & 63) == 63) i1 = corank(s, pb, L, so + 32);
  else i1 = nxt;
  int na = i1 - i0;
  int j1 = so + 32 - i1;
#pragma unroll
  for (int q = 0; q < 32; ++q) {
    int idx = (q < na) ? (pb + i0 + q)
                       : (pb + L + j1 - 1 - (q - na));
    v[q] = s[SIDX(idx)];
  }
#pragma unroll
  for (int j = 16; j >= 1; j >>= 1) {
#pragma unroll
    for (int q = 0; q < 32; ++q) {
      if ((q & j) == 0) {
        float a = v[q], b = v[q | j];
        v[q] = fminf(a, b);
        v[q | j] = fmaxf(a, b);
      }
    }
  }
  if (crosswave) __syncthreads();
}

__device__ __forceinline__ void mergesort_col(float (&v)[32], float* __restrict__ s,
                                              int t, int bi) {
  for (int L = 32; L <= 1024; L <<= 1) merge_round(v, s, t, bi, L, false);
  for (int L = 2048; L <= 8192; L <<= 1) merge_round(v, s, t, bi, L, true);
}

__global__ __launch_bounds__(512, 4) void sortdiff_kernel(
    const float* __restrict__ proj1, const float* __restrict__ proj2,
    float* __restrict__ sum, int m) {
  __shared__ float s[16384];
  int t = threadIdx.x;
  int col = blockIdx.x;  // 0..511
  const float INF = __builtin_huge_valf();
  float va[32], vb[32];
  int bi = t << 5;

  const float* pa = proj1 + (size_t)col * 16384;
  const float* pbp = proj2 + (size_t)col * 16384;
  if (bi < m) {
#pragma unroll
    for (int i = 0; i < 8; ++i) {
      float4 A4 = *(const float4*)(pa + bi + i * 4);
      va[i * 4 + 0] = A4.x; va[i * 4 + 1] = A4.y;
      va[i * 4 + 2] = A4.z; va[i * 4 + 3] = A4.w;
      float4 B4 = *(const float4*)(pbp + bi + i * 4);
      vb[i * 4 + 0] = B4.x; vb[i * 4 + 1] = B4.y;
      vb[i * 4 + 2] = B4.z; vb[i * 4 + 3] = B4.w;
    }
  } else {
#pragma unroll
    for (int r = 0; r < 32; ++r) { va[r] = INF; vb[r] = INF; }
  }

  // ---- in-thread bitonic-32 sort, both columns interleaved (2x ILP)
#pragma unroll
  for (int k = 2; k <= 32; k <<= 1) {
#pragma unroll
    for (int j = k >> 1; j >= 1; j >>= 1) {
#pragma unroll
      for (int r = 0; r < 32; ++r) {
        if ((r & j) == 0) {
          bool up = ((r & k) == 0);   // k=32: always true for r<32
          float a0 = va[r], b0 = va[r | j];
          float lo0 = fminf(a0, b0), hi0 = fmaxf(a0, b0);
          va[r] = up ? lo0 : hi0;
          va[r | j] = up ? hi0 : lo0;
          float a1 = vb[r], b1 = vb[r | j];
          float lo1 = fminf(a1, b1), hi1 = fmaxf(a1, b1);
          vb[r] = up ? lo1 : hi1;
          vb[r | j] = up ? hi1 : lo1;
        }
      }
    }
  }

  // column A: 9 merge-path rounds; result stays in va. exits synced.
  mergesort_col(va, s, t, bi);
  // column B: reuse LDS; result lands in vb.
  mergesort_col(vb, s, t, bi);

  float acc = 0.f;
  if (bi < m) {
#pragma unroll
    for (int q = 0; q < 32; ++q) acc += fabsf(va[q] - vb[q]);
  }

#pragma unroll
  for (int o = 32; o > 0; o >>= 1) acc += __shfl_down(acc, o, 64);
  if ((t & 63) == 0) s[t >> 6] = acc;
  __syncthreads();
  if (t == 0) {
    float tot = 0.f;
    for (int i = 0; i < 8; ++i) tot += s[i];
    atomicAdd(sum, tot);
  }
}

__global__ void final_kernel(const float* __restrict__ sums, float* __restrict__ out) {
  float r = sums[0] * (1.f / 8388608.f) + sums[1] * (1.f / 8388608.f) +
            sums[2] * (1.f / 8388608.f) + sums[3] * (1.f / 8388608.f) +
            sums[4] * (1.f / 6553600.f);
  out[0] = r * (1000.f / 5.f);
}

// ---------------------------------------------------------------------------

extern "C" void kernel_launch(void* const* d_in, const int* in_sizes, int n_in,
                              void* d_out, int out_size, void* d_ws, size_t ws_size,
                              hipStream_t stream) {
  const float* xin = (const float*)d_in[0];
  const float* yin = (const float*)d_in[1];
  float* out = (float*)d_out;

  char* base = (char*)d_ws;
  size_t off = 0;
  auto alloc = [&](size_t nfloats) -> float* {
    float* p = (float*)(base + off);
    off += ((nfloats * 4) + 255) & ~(size_t)255;
    return p;
  };
  float* gX[5];
  float* gY[5];
  gX[0] = (float*)xin;
  gY[0] = (float*)yin;
  gX[1] = alloc(6291456); gX[2] = alloc(1572864); gX[3] = alloc(393216); gX[4] = alloc(98304);
  gY[1] = alloc(6291456); gY[2] = alloc(1572864); gY[3] = alloc(393216); gY[4] = alloc(98304);
  uint32_t* p1 = (uint32_t*)alloc((size_t)16384 * 160);
  uint32_t* p2 = (uint32_t*)alloc((size_t)16384 * 160);
  float* rnd = alloc((size_t)5 * 75264);
  float* inv1s = alloc(5 * 512);
  float* scS = alloc((size_t)5 * 1536);
  float* redg = alloc(16);
  uint32_t* Bt1 = (uint32_t*)alloc(160 * 512);
  uint32_t* Bt2 = (uint32_t*)alloc(160 * 512);
  float* proj1 = alloc((size_t)16384 * 512);
  float* proj2 = alloc((size_t)16384 * 512);
  float* part1 = alloc(EXB * 6);
  float* part2 = alloc(EXB * 6);
  float* misc = alloc(128);

  static const int Hs[5] = {256, 128, 64, 32, 16};

  Keys ks;
  for (int l = 0; l < 5; ++l) { ks.a[l] = g_tbl.kp0[l]; ks.b[l] = g_tbl.kp1[l]; }
  randgen_kernel<<<1470, 256, 0, stream>>>(rnd, ks, misc);
  rndstats_kernel<<<10, 256, 0, stream>>>(rnd, inv1s, scS);

  // fused X+Y separable pyramid downsampling
  down_kernel<<<2 * 384 * 32, 256, 0, stream>>>(xin, gX[1], yin, gY[1], 256, 2, 8);
  down_kernel<<<2 * 384 * 8, 256, 0, stream>>>(gX[1], gX[2], gY[1], gY[2], 128, 3, 7);
  down_kernel<<<2 * 384 * 2, 256, 0, stream>>>(gX[2], gX[3], gY[2], gY[3], 64, 4, 6);
  down_kernel<<<2 * 384 * 1, 256, 0, stream>>>(gX[3], gX[4], gY[3], gY[4], 32, 4, 5);

  for (int l = 0; l < 5; ++l) {
    int H = Hs[l];
    int Wm6 = H - 6;
    int n = Wm6 * Wm6;
    int nd = n < 128 ? n : 128;
    int M = 128 * nd;
    extract_kernel<<<2 * EXB, 256, 0, stream>>>(
        gX[l], (l < 4) ? gX[l + 1] : nullptr, p1, part1,
        gY[l], (l < 4) ? gY[l + 1] : nullptr, p2, part2,
        g_tbl.rcs[l], H, nd, (l < 4) ? 1 : 0, M);
    redpart_kernel<<<1, 256, 0, stream>>>(part1, part2, redg);
    prep_kernel<<<512, 192, 0, stream>>>(rnd + (size_t)l * 75264, inv1s + l * 512,
                                         scS + (size_t)l * 1536, redg, Bt1, Bt2,
                                         (float)M * 49.f);
    dim3 gg(M / 128, 4, 2);
    gemm_kernel<<<gg, 256, 0, stream>>>(p1, Bt1, p2, Bt2, proj1, proj2, M);
    sortdiff_kernel<<<512, 512, 0, stream>>>(proj1, proj2, misc + l, M);
  }
  final_kernel<<<1, 1, 0, stream>>>(misc, out);
}